// Round 2
// baseline (2214.375 us; speedup 1.0000x reference)
//
#include <hip/hip_runtime.h>
#include <math.h>

#define S0 3600
#define S1 720
#define S2 144
#define S3 36
#define S4 9
#define NEGF (-1e30f)

// ---- workspace layout (bytes). Peak 74.72 MB; intermediates alias dead x0.
static constexpr size_t OFF_X0  = 0;                                    // f32 [3600*3600] = 51,840,000
static constexpr size_t OFF_M0B = (size_t)S0 * S0 * 4;                  // u32 bitfield [3600*3600 bits] = 1,620,000
static constexpr size_t OFF_Y1  = OFF_M0B + 1620000;                    // f32 [720*720*10] @53,460,000
static constexpr size_t OFF_M1  = OFF_Y1 + (size_t)S1 * S1 * 10 * 4;    // u8  [720*720]    @74,196,000 (ends 74,714,400)
// aliased into dead x0 region (used from conv2 onward):
static constexpr size_t OFF_Y2  = 0;                                    // f32 [144*144*64]  = 5,308,416
static constexpr size_t OFF_M2  = OFF_Y2 + (size_t)S2 * S2 * 64 * 4;    // u8  [144*144]
static constexpr size_t OFF_C3  = OFF_M2 + 20736;                       // f32 [144*144*128] = 10,614,528
static constexpr size_t OFF_Y3  = OFF_C3 + (size_t)S2 * S2 * 128 * 4;   // f32 [36*36*128]
static constexpr size_t OFF_M3  = OFF_Y3 + (size_t)S3 * S3 * 128 * 4;   // u8  [36*36]
static constexpr size_t OFF_C4  = OFF_M3 + 1296;                        // f32 [36*36*256] = 1,327,104
static constexpr size_t OFF_Y4  = OFF_C4 + (size_t)S3 * S3 * 256 * 4;   // f32 [9*9*256]
static constexpr size_t OFF_H1  = OFF_Y4 + (size_t)S4 * S4 * 256 * 4;   // f32 [32]  (ends ~18,018,704 < 51,840,000)

__device__ __forceinline__ float eluf(float x) { return x > 0.f ? x : expm1f(x); }
__device__ __forceinline__ int bit_get(const unsigned* mb, int idx) {
    return (mb[idx >> 5] >> (idx & 31)) & 1;
}

// ---- scatter points onto dense grid -----------------------------------------
__global__ __launch_bounds__(256) void k_scatter(const int* __restrict__ coords,
                                                 const float* __restrict__ feats,
                                                 float* __restrict__ x0,
                                                 unsigned* __restrict__ m0b, int P) {
    int i = blockIdx.x * 256 + threadIdx.x;
    if (i >= P) return;
    int r = coords[2 * i], c = coords[2 * i + 1];
    int idx = r * S0 + c;
    atomicAdd(&x0[idx], feats[i]);
    atomicOr(&m0b[idx >> 5], 1u << (idx & 31));
}

// ---- layer 1: conv 5x5 1->10 (gated at active sites) + ELU + maxpool5 -------
__global__ __launch_bounds__(256) void k_l1(const float* __restrict__ x0,
                                            const unsigned* __restrict__ m0b,
                                            const float* __restrict__ w1,
                                            float* __restrict__ y1,
                                            unsigned char* __restrict__ m1) {
    int t = blockIdx.x * 256 + threadIdx.x;
    if (t >= S1 * S1) return;
    int pr = t / S1, pc = t % S1;
    int r0 = pr * 5, c0 = pc * 5;
    float mx[10];
#pragma unroll
    for (int ch = 0; ch < 10; ch++) mx[ch] = NEGF;
    bool any = false;
    for (int dy = 0; dy < 5; dy++) {
        for (int dx = 0; dx < 5; dx++) {
            int rr = r0 + dy, cc = c0 + dx;
            if (!bit_get(m0b, rr * S0 + cc)) continue;
            any = true;
            float acc[10];
#pragma unroll
            for (int ch = 0; ch < 10; ch++) acc[ch] = 0.f;
            for (int ky = 0; ky < 5; ky++) {
                int ir = rr + ky - 2;
                if (ir < 0 || ir >= S0) continue;
                for (int kx = 0; kx < 5; kx++) {
                    int ic = cc + kx - 2;
                    if (ic < 0 || ic >= S0) continue;
                    float xv = x0[(size_t)ir * S0 + ic];
                    const float* wp = &w1[(ky * 5 + kx) * 10];
#pragma unroll
                    for (int ch = 0; ch < 10; ch++) acc[ch] = fmaf(xv, wp[ch], acc[ch]);
                }
            }
#pragma unroll
            for (int ch = 0; ch < 10; ch++) mx[ch] = fmaxf(mx[ch], acc[ch]);
        }
    }
    float* yo = &y1[(size_t)t * 10];
#pragma unroll
    for (int ch = 0; ch < 10; ch++) yo[ch] = any ? eluf(mx[ch]) : 0.f;
    m1[t] = any ? 1 : 0;
}

// ---- layer 2: fused conv 5x5 10->64 + ELU + maxpool5 (simple form) ----------
// one thread per (pool site, out channel)
__global__ __launch_bounds__(256) void k_conv2p(const float* __restrict__ y1,
                                                const unsigned char* __restrict__ m1,
                                                const float* __restrict__ w2,
                                                float* __restrict__ y2,
                                                unsigned char* __restrict__ m2) {
    int id = blockIdx.x * 256 + threadIdx.x;   // < 144*144*64
    int co = id & 63, p = id >> 6;
    int pr = p / S2, pc = p % S2;
    float mx = NEGF;
    bool any = false;
    for (int dy = 0; dy < 5; dy++) {
        for (int dx = 0; dx < 5; dx++) {
            int gr = pr * 5 + dy, gc = pc * 5 + dx;
            if (!m1[gr * S1 + gc]) continue;
            any = true;
            float acc = 0.f;
            for (int ky = 0; ky < 5; ky++) {
                int ir = gr + ky - 2;
                if (ir < 0 || ir >= S1) continue;
                for (int kx = 0; kx < 5; kx++) {
                    int ic = gc + kx - 2;
                    if (ic < 0 || ic >= S1) continue;
                    const float* xp = &y1[((size_t)ir * S1 + ic) * 10];
                    const float* wp = &w2[(ky * 5 + kx) * 10 * 64 + co];
#pragma unroll
                    for (int ci = 0; ci < 10; ci++) acc = fmaf(xp[ci], wp[ci * 64], acc);
                }
            }
            mx = fmaxf(mx, acc);
        }
    }
    y2[(size_t)p * 64 + co] = any ? eluf(mx) : 0.f;
    if (co == 0) m2[p] = any ? 1 : 0;
}

// ---- layer 3 conv (dense, gated): 5x5 64->128 at 144^2 ----------------------
__global__ __launch_bounds__(256) void k_conv3d(const float* __restrict__ y2,
                                                const unsigned char* __restrict__ m2,
                                                const float* __restrict__ w3,
                                                float* __restrict__ c3) {
    int id = blockIdx.x * 256 + threadIdx.x;   // < 144*144*128
    int co = id & 127, s = id >> 7;
    int sr = s / S2, sc = s % S2;
    float acc = 0.f;
    if (m2[s]) {
        for (int ky = 0; ky < 5; ky++) {
            int ir = sr + ky - 2;
            if (ir < 0 || ir >= S2) continue;
            for (int kx = 0; kx < 5; kx++) {
                int ic = sc + kx - 2;
                if (ic < 0 || ic >= S2) continue;
                const float* xp = &y2[((size_t)ir * S2 + ic) * 64];
                const float* wp = &w3[(ky * 5 + kx) * 64 * 128 + co];
#pragma unroll 16
                for (int ci = 0; ci < 64; ci++) acc = fmaf(xp[ci], wp[ci * 128], acc);
            }
        }
    }
    c3[(size_t)s * 128 + co] = acc;
}

// ---- layer 3 maxpool 4 -> 36^2 ---------------------------------------------
__global__ __launch_bounds__(256) void k_pool3(const float* __restrict__ c3,
                                               const unsigned char* __restrict__ m2,
                                               float* __restrict__ y3,
                                               unsigned char* __restrict__ m3) {
    int id = blockIdx.x * 256 + threadIdx.x;   // < 36*36*128
    int co = id & 127, p = id >> 7;
    int ppr = p / S3, ppc = p % S3;
    float mx = NEGF;
    bool any = false;
    for (int dy = 0; dy < 4; dy++)
        for (int dx = 0; dx < 4; dx++) {
            int s = (ppr * 4 + dy) * S2 + ppc * 4 + dx;
            if (m2[s]) { any = true; mx = fmaxf(mx, c3[(size_t)s * 128 + co]); }
        }
    y3[(size_t)p * 128 + co] = any ? eluf(mx) : 0.f;
    if (co == 0) m3[p] = any ? 1 : 0;
}

// ---- layer 4 conv (dense, gated): 5x5 128->256 at 36^2 ----------------------
__global__ __launch_bounds__(256) void k_conv4d(const float* __restrict__ y3,
                                                const unsigned char* __restrict__ m3,
                                                const float* __restrict__ w4,
                                                float* __restrict__ c4) {
    int id = blockIdx.x * 256 + threadIdx.x;   // < 36*36*256
    int co = id & 255, s = id >> 8;
    int sr = s / S3, sc = s % S3;
    float acc = 0.f;
    if (m3[s]) {
        for (int ky = 0; ky < 5; ky++) {
            int ir = sr + ky - 2;
            if (ir < 0 || ir >= S3) continue;
            for (int kx = 0; kx < 5; kx++) {
                int ic = sc + kx - 2;
                if (ic < 0 || ic >= S3) continue;
                const float* xp = &y3[((size_t)ir * S3 + ic) * 128];
                const float* wp = &w4[(ky * 5 + kx) * 128 * 256 + co];
#pragma unroll 16
                for (int ci = 0; ci < 128; ci++) acc = fmaf(xp[ci], wp[ci * 256], acc);
            }
        }
    }
    c4[(size_t)s * 256 + co] = acc;
}

// ---- layer 4 maxpool 4 -> 9^2 ----------------------------------------------
__global__ __launch_bounds__(256) void k_pool4(const float* __restrict__ c4,
                                               const unsigned char* __restrict__ m3,
                                               float* __restrict__ y4) {
    int id = blockIdx.x * 256 + threadIdx.x;   // < 81*256 = 20736
    int co = id & 255, p = id >> 8;
    int ppr = p / S4, ppc = p % S4;
    float mx = NEGF;
    bool any = false;
    for (int dy = 0; dy < 4; dy++)
        for (int dx = 0; dx < 4; dx++) {
            int s = (ppr * 4 + dy) * S3 + ppc * 4 + dx;
            if (m3[s]) { any = true; mx = fmaxf(mx, c4[(size_t)s * 256 + co]); }
        }
    y4[(size_t)p * 256 + co] = any ? eluf(mx) : 0.f;
}

// ---- fc1 (deterministic): 32 blocks, block j computes h1[j] -----------------
__global__ __launch_bounds__(256) void k_fc1(const float* __restrict__ y4,
                                             const float* __restrict__ fc1_w,
                                             float* __restrict__ h1) {
    __shared__ float part[256];
    int j = blockIdx.x;                    // 0..31
    int tid = threadIdx.x;
    float s = 0.f;
    for (int i = tid; i < 256 * 81; i += 256) {
        int c = i / 81, rem = i % 81;      // NCHW flatten: i = c*81 + h*9 + w
        s = fmaf(y4[(size_t)rem * 256 + c], fc1_w[(size_t)i * 32 + j], s);
    }
    part[tid] = s;
    __syncthreads();
    for (int off = 128; off > 0; off >>= 1) {
        if (tid < off) part[tid] += part[tid + off];
        __syncthreads();
    }
    if (tid == 0) h1[j] = part[0];
}

// ---- fc2 + softmax ----------------------------------------------------------
__global__ __launch_bounds__(64) void k_fc2(const float* __restrict__ h1,
                                            const float* __restrict__ fc1_b,
                                            const float* __restrict__ fc2_w,
                                            const float* __restrict__ fc2_b,
                                            float* __restrict__ out) {
    __shared__ float hv[32];
    __shared__ float lg[5];
    int tid = threadIdx.x;
    if (tid < 32) hv[tid] = eluf(h1[tid] + fc1_b[tid]);
    __syncthreads();
    if (tid < 5) {
        float s = fc2_b[tid];
        for (int j = 0; j < 32; j++) s = fmaf(hv[j], fc2_w[j * 5 + tid], s);
        lg[tid] = s;
    }
    __syncthreads();
    if (tid == 0) {
        float m = lg[0];
        for (int k = 1; k < 5; k++) m = fmaxf(m, lg[k]);
        float e[5], sum = 0.f;
        for (int k = 0; k < 5; k++) { e[k] = expf(lg[k] - m); sum += e[k]; }
        for (int k = 0; k < 5; k++) out[k] = e[k] / sum;
    }
}

extern "C" void kernel_launch(void* const* d_in, const int* in_sizes, int n_in,
                              void* d_out, int out_size, void* d_ws, size_t ws_size,
                              hipStream_t stream) {
    const int* coords = (const int*)d_in[0];
    const float* feats = (const float*)d_in[1];
    const float* w1 = (const float*)d_in[2];
    const float* w2 = (const float*)d_in[3];
    const float* w3 = (const float*)d_in[4];
    const float* w4 = (const float*)d_in[5];
    const float* fc1w = (const float*)d_in[6];
    const float* fc1b = (const float*)d_in[7];
    const float* fc2w = (const float*)d_in[8];
    const float* fc2b = (const float*)d_in[9];
    float* out = (float*)d_out;
    char* ws = (char*)d_ws;
    float* x0 = (float*)(ws + OFF_X0);
    unsigned* m0b = (unsigned*)(ws + OFF_M0B);
    float* y1 = (float*)(ws + OFF_Y1);
    unsigned char* m1g = (unsigned char*)(ws + OFF_M1);
    float* y2 = (float*)(ws + OFF_Y2);
    unsigned char* m2g = (unsigned char*)(ws + OFF_M2);
    float* c3 = (float*)(ws + OFF_C3);
    float* y3 = (float*)(ws + OFF_Y3);
    unsigned char* m3g = (unsigned char*)(ws + OFF_M3);
    float* c4 = (float*)(ws + OFF_C4);
    float* y4 = (float*)(ws + OFF_Y4);
    float* h1 = (float*)(ws + OFF_H1);
    int P = in_sizes[1];

    // zero x0 + m0 bitfield
    hipMemsetAsync(ws, 0, OFF_Y1, stream);
    k_scatter<<<(P + 255) / 256, 256, 0, stream>>>(coords, feats, x0, m0b, P);
    k_l1<<<(S1 * S1 + 255) / 256, 256, 0, stream>>>(x0, m0b, w1, y1, m1g);
    k_conv2p<<<(S2 * S2 * 64) / 256, 256, 0, stream>>>(y1, m1g, w2, y2, m2g);
    k_conv3d<<<(S2 * S2 * 128) / 256, 256, 0, stream>>>(y2, m2g, w3, c3);
    k_pool3<<<(S3 * S3 * 128) / 256, 256, 0, stream>>>(c3, m2g, y3, m3g);
    k_conv4d<<<(S3 * S3 * 256) / 256, 256, 0, stream>>>(y3, m3g, w4, c4);
    k_pool4<<<(S4 * S4 * 256) / 256, 256, 0, stream>>>(c4, m3g, y4);
    k_fc1<<<32, 256, 0, stream>>>(y4, fc1w, h1);
    k_fc2<<<1, 64, 0, stream>>>(h1, fc1b, fc2w, fc2b, out);
}

// Round 3
// 945.113 us; speedup vs baseline: 2.3430x; 2.3430x over previous
//
#include <hip/hip_runtime.h>
#include <math.h>

#define S0 3600
#define S1 720
#define S2 144
#define S3 36
#define S4 9
#define NEGF (-1e30f)

// ---- workspace layout (bytes). Peak 74.72 MB (same as passing round 2).
static constexpr size_t OFF_X0  = 0;                                    // f32 [3600*3600] = 51,840,000
static constexpr size_t OFF_M0B = (size_t)S0 * S0 * 4;                  // u32 bitfield    = 1,620,000
static constexpr size_t OFF_Y1  = OFF_M0B + 1620000;                    // f32 [720*720*10] @53,460,000
static constexpr size_t OFF_M1  = OFF_Y1 + (size_t)S1 * S1 * 10 * 4;    // u8  [720*720]    @74,196,000 (ends 74,714,400)
// aliased into dead x0 region (used from conv2 onward):
static constexpr size_t OFF_Y2  = 0;                                    // f32 [144*144*64]  = 5,308,416
static constexpr size_t OFF_M2  = OFF_Y2 + (size_t)S2 * S2 * 64 * 4;    // u8  [144*144]
static constexpr size_t OFF_Y3  = OFF_M2 + 20736;                       // f32 [36*36*128]
static constexpr size_t OFF_M3  = OFF_Y3 + (size_t)S3 * S3 * 128 * 4;   // u8  [36*36]
static constexpr size_t OFF_Y4  = OFF_M3 + 1296;                        // f32 [9*9*256]
static constexpr size_t OFF_H1  = OFF_Y4 + (size_t)S4 * S4 * 256 * 4;   // f32 [32]

__device__ __forceinline__ float eluf(float x) { return x > 0.f ? x : expm1f(x); }
__device__ __forceinline__ int bit_get(const unsigned* mb, int idx) {
    return (mb[idx >> 5] >> (idx & 31)) & 1;
}

// ---- scatter points onto dense grid -----------------------------------------
__global__ __launch_bounds__(256) void k_scatter(const int* __restrict__ coords,
                                                 const float* __restrict__ feats,
                                                 float* __restrict__ x0,
                                                 unsigned* __restrict__ m0b, int P) {
    int i = blockIdx.x * 256 + threadIdx.x;
    if (i >= P) return;
    int r = coords[2 * i], c = coords[2 * i + 1];
    int idx = r * S0 + c;
    atomicAdd(&x0[idx], feats[i]);
    atomicOr(&m0b[idx >> 5], 1u << (idx & 31));
}

// ---- layer 1: conv 5x5 1->10 (gated at active sites) + ELU + maxpool5 -------
__global__ __launch_bounds__(256) void k_l1(const float* __restrict__ x0,
                                            const unsigned* __restrict__ m0b,
                                            const float* __restrict__ w1,
                                            float* __restrict__ y1,
                                            unsigned char* __restrict__ m1) {
    int t = blockIdx.x * 256 + threadIdx.x;
    if (t >= S1 * S1) return;
    int pr = t / S1, pc = t % S1;
    int r0 = pr * 5, c0 = pc * 5;
    float mx[10];
#pragma unroll
    for (int ch = 0; ch < 10; ch++) mx[ch] = NEGF;
    bool any = false;
    for (int dy = 0; dy < 5; dy++) {
        for (int dx = 0; dx < 5; dx++) {
            int rr = r0 + dy, cc = c0 + dx;
            if (!bit_get(m0b, rr * S0 + cc)) continue;
            any = true;
            float acc[10];
#pragma unroll
            for (int ch = 0; ch < 10; ch++) acc[ch] = 0.f;
            for (int ky = 0; ky < 5; ky++) {
                int ir = rr + ky - 2;
                if (ir < 0 || ir >= S0) continue;
                for (int kx = 0; kx < 5; kx++) {
                    int ic = cc + kx - 2;
                    if (ic < 0 || ic >= S0) continue;
                    float xv = x0[(size_t)ir * S0 + ic];
                    const float* wp = &w1[(ky * 5 + kx) * 10];
#pragma unroll
                    for (int ch = 0; ch < 10; ch++) acc[ch] = fmaf(xv, wp[ch], acc[ch]);
                }
            }
#pragma unroll
            for (int ch = 0; ch < 10; ch++) mx[ch] = fmaxf(mx[ch], acc[ch]);
        }
    }
    float* yo = &y1[(size_t)t * 10];
#pragma unroll
    for (int ch = 0; ch < 10; ch++) yo[ch] = any ? eluf(mx[ch]) : 0.f;
    m1[t] = any ? 1 : 0;
}

// ---- layer 2: fused conv 5x5 10->64 (cell-gated) + ELU + maxpool5 -----------
// one wave (64 threads = 64 out channels) per pool cell; LDS window 9x9x10
// padded to stride 12 for aligned float4 LDS reads.
__global__ __launch_bounds__(64) void k_l2(const float* __restrict__ y1,
                                           const unsigned char* __restrict__ m1,
                                           const float* __restrict__ w2,
                                           float* __restrict__ y2,
                                           unsigned char* __restrict__ m2) {
    __shared__ float win[81 * 12];      // 9x9 cells x 12 (10ch + 2 pad)
    __shared__ unsigned char sm[81];
    int b = blockIdx.x;
    int pr = b / S2, pc = b % S2;
    int r0 = pr * 5 - 2, c0 = pc * 5 - 2;
    int tid = threadIdx.x;
    for (int k = tid; k < 81; k += 64) {
        int gr = r0 + k / 9, gc = c0 + k % 9;
        bool ok = (gr >= 0 && gr < S1 && gc >= 0 && gc < S1);
        sm[k] = ok ? m1[gr * S1 + gc] : (unsigned char)0;
        float* dst = &win[k * 12];
        if (ok) {
            const float2* src = (const float2*)&y1[((size_t)gr * S1 + gc) * 10];
#pragma unroll
            for (int q = 0; q < 5; q++) ((float2*)dst)[q] = src[q];
        } else {
#pragma unroll
            for (int q = 0; q < 5; q++) ((float2*)dst)[q] = make_float2(0.f, 0.f);
        }
        dst[10] = 0.f; dst[11] = 0.f;
    }
    __syncthreads();
    int c = tid;
    unsigned mbits = 0;
#pragma unroll
    for (int cell = 0; cell < 25; cell++) {
        if (sm[(2 + cell / 5) * 9 + (2 + cell % 5)]) mbits |= (1u << cell);
    }
    mbits = (unsigned)__builtin_amdgcn_readfirstlane((int)mbits);
    float acc[25];
#pragma unroll
    for (int i = 0; i < 25; i++) acc[i] = 0.f;
    for (int t5 = 0; t5 < 25; t5++) {
        float w[10];
#pragma unroll
        for (int ci = 0; ci < 10; ci++) w[ci] = w2[(t5 * 10 + ci) * 64 + c];
        int base = (t5 / 5) * 9 + (t5 % 5);
#pragma unroll
        for (int cell = 0; cell < 25; cell++) {
            if (mbits & (1u << cell)) {
                const float4* xp = (const float4*)&win[(base + (cell / 5) * 9 + (cell % 5)) * 12];
                float4 xa = xp[0], xb = xp[1], xc = xp[2];
                float a = acc[cell];
                a = fmaf(xa.x, w[0], a); a = fmaf(xa.y, w[1], a);
                a = fmaf(xa.z, w[2], a); a = fmaf(xa.w, w[3], a);
                a = fmaf(xb.x, w[4], a); a = fmaf(xb.y, w[5], a);
                a = fmaf(xb.z, w[6], a); a = fmaf(xb.w, w[7], a);
                a = fmaf(xc.x, w[8], a); a = fmaf(xc.y, w[9], a);
                acc[cell] = a;
            }
        }
    }
    float mx = NEGF;
#pragma unroll
    for (int cell = 0; cell < 25; cell++)
        if (mbits & (1u << cell)) mx = fmaxf(mx, acc[cell]);
    bool any = (mbits != 0);
    y2[((size_t)pr * S2 + pc) * 64 + c] = any ? eluf(mx) : 0.f;
    if (c == 0) m2[pr * S2 + pc] = any ? 1 : 0;
}

// ---- layer 3: fused conv 5x5 64->128 + ELU + maxpool4 -> 36^2 ---------------
// one block (256 thr) per pool cell; 8x8x64 window in LDS; 2 cells x 4 co/thr.
__global__ __launch_bounds__(256) void k_l3(const float* __restrict__ y2,
                                            const unsigned char* __restrict__ m2,
                                            const float* __restrict__ w3,
                                            float* __restrict__ y3,
                                            unsigned char* __restrict__ m3) {
    __shared__ float win[8 * 8 * 64];   // 16 KB
    __shared__ float red[8][128];       // 4 KB
    __shared__ unsigned char sm[16];
    int b = blockIdx.x;                  // 0..1295
    int ppr = b / S3, ppc = b % S3;
    int r0 = ppr * 4 - 2, c0 = ppc * 4 - 2;
    int tid = threadIdx.x;
    float4* win4 = (float4*)win;
    for (int k = tid; k < 1024; k += 256) {
        int cellk = k >> 4, q = k & 15;
        int gr = r0 + (cellk >> 3), gc = c0 + (cellk & 7);
        float4 v = make_float4(0.f, 0.f, 0.f, 0.f);
        if (gr >= 0 && gr < S2 && gc >= 0 && gc < S2)
            v = ((const float4*)y2)[((size_t)gr * S2 + gc) * 16 + q];
        win4[k] = v;
    }
    if (tid < 16) sm[tid] = m2[(ppr * 4 + (tid >> 2)) * S2 + ppc * 4 + (tid & 3)];
    __syncthreads();
    int c4 = (tid & 31) * 4;             // out-channel base (0..124)
    int cellq = tid >> 5;                // 0..7 -> 2 cells each
    int cell0 = cellq * 2, cell1 = cellq * 2 + 1;
    int d0 = ((cell0 >> 2) * 8 + (cell0 & 3)) * 64;
    int d1 = ((cell1 >> 2) * 8 + (cell1 & 3)) * 64;
    float4 a0 = make_float4(0.f, 0.f, 0.f, 0.f), a1 = a0;
    for (int t5 = 0; t5 < 25; t5++) {
        const float* wbase = &win[((t5 / 5) * 8 + (t5 % 5)) * 64];
        const float4* wv = (const float4*)&w3[(size_t)(t5 * 64) * 128 + c4];
#pragma unroll 8
        for (int ci = 0; ci < 64; ci++) {
            float4 w = wv[(size_t)ci * 32];
            float xa = wbase[d0 + ci];
            float xb = wbase[d1 + ci];
            a0.x = fmaf(xa, w.x, a0.x); a0.y = fmaf(xa, w.y, a0.y);
            a0.z = fmaf(xa, w.z, a0.z); a0.w = fmaf(xa, w.w, a0.w);
            a1.x = fmaf(xb, w.x, a1.x); a1.y = fmaf(xb, w.y, a1.y);
            a1.z = fmaf(xb, w.z, a1.z); a1.w = fmaf(xb, w.w, a1.w);
        }
    }
    float4 n4 = make_float4(NEGF, NEGF, NEGF, NEGF);
    float4 v0 = sm[cell0] ? a0 : n4;
    float4 v1 = sm[cell1] ? a1 : n4;
    float4 vm;
    vm.x = fmaxf(v0.x, v1.x); vm.y = fmaxf(v0.y, v1.y);
    vm.z = fmaxf(v0.z, v1.z); vm.w = fmaxf(v0.w, v1.w);
    *(float4*)&red[cellq][c4] = vm;
    __syncthreads();
    bool any = false;
#pragma unroll
    for (int i = 0; i < 16; i++) any |= (sm[i] != 0);
    if (tid < 128) {
        float m = red[0][tid];
#pragma unroll
        for (int q = 1; q < 8; q++) m = fmaxf(m, red[q][tid]);
        y3[(size_t)b * 128 + tid] = any ? eluf(m) : 0.f;
    }
    if (tid == 0) m3[b] = any ? 1 : 0;
}

// ---- layer 4: fused conv 5x5 128->256 + ELU + maxpool4 -> 9^2 ---------------
// block = (pool cell, 64-ch group); 8x8x128 window in LDS, row stride 132
// (pad +4 floats) to avoid 4-way same-bank conflict across the 4 cell groups.
__global__ __launch_bounds__(256) void k_l4(const float* __restrict__ y3,
                                            const unsigned char* __restrict__ m3,
                                            const float* __restrict__ w4,
                                            float* __restrict__ y4) {
    __shared__ float win[64 * 132];     // 33.8 KB
    __shared__ float red[16][64];       // 4 KB
    __shared__ unsigned char sm[16];
    int b = blockIdx.x;                  // 0..323
    int pp = b >> 2, cg = b & 3;
    int ppr = pp / S4, ppc = pp % S4;
    int r0 = ppr * 4 - 2, c0 = ppc * 4 - 2;
    int tid = threadIdx.x;
    for (int k = tid; k < 2048; k += 256) {
        int cellk = k >> 5, q = k & 31;
        int gr = r0 + (cellk >> 3), gc = c0 + (cellk & 7);
        float4 v = make_float4(0.f, 0.f, 0.f, 0.f);
        if (gr >= 0 && gr < S3 && gc >= 0 && gc < S3)
            v = ((const float4*)y3)[((size_t)gr * S3 + gc) * 32 + q];
        ((float4*)&win[cellk * 132])[q] = v;
    }
    if (tid < 16) sm[tid] = m3[(ppr * 4 + (tid >> 2)) * S3 + ppc * 4 + (tid & 3)];
    __syncthreads();
    int c4g = tid & 15, cellq = tid >> 4;  // 16 ch-groups x 16 cells
    int c4 = cg * 64 + c4g * 4;
    int dd = ((cellq >> 2) * 8 + (cellq & 3)) * 132;
    float4 a = make_float4(0.f, 0.f, 0.f, 0.f);
    for (int t5 = 0; t5 < 25; t5++) {
        const float* wbase = &win[((t5 / 5) * 8 + (t5 % 5)) * 132 + dd];
        const float4* wv = (const float4*)&w4[(size_t)(t5 * 128) * 256 + c4];
#pragma unroll 8
        for (int ci = 0; ci < 128; ci++) {
            float4 w = wv[(size_t)ci * 64];
            float xv = wbase[ci];
            a.x = fmaf(xv, w.x, a.x); a.y = fmaf(xv, w.y, a.y);
            a.z = fmaf(xv, w.z, a.z); a.w = fmaf(xv, w.w, a.w);
        }
    }
    float4 n4 = make_float4(NEGF, NEGF, NEGF, NEGF);
    float4 v = sm[cellq] ? a : n4;
    *(float4*)&red[cellq][c4g * 4] = v;
    __syncthreads();
    bool any = false;
#pragma unroll
    for (int i = 0; i < 16; i++) any |= (sm[i] != 0);
    if (tid < 64) {
        float m = red[0][tid];
#pragma unroll
        for (int q = 1; q < 16; q++) m = fmaxf(m, red[q][tid]);
        y4[(size_t)pp * 256 + cg * 64 + tid] = any ? eluf(m) : 0.f;
    }
}

// ---- fc1 (deterministic): 32 blocks, block j computes h1[j] -----------------
__global__ __launch_bounds__(256) void k_fc1(const float* __restrict__ y4,
                                             const float* __restrict__ fc1_w,
                                             float* __restrict__ h1) {
    __shared__ float part[256];
    int j = blockIdx.x;                    // 0..31
    int tid = threadIdx.x;
    float s = 0.f;
    for (int i = tid; i < 256 * 81; i += 256) {
        int c = i / 81, rem = i % 81;      // NCHW flatten: i = c*81 + h*9 + w
        s = fmaf(y4[(size_t)rem * 256 + c], fc1_w[(size_t)i * 32 + j], s);
    }
    part[tid] = s;
    __syncthreads();
    for (int off = 128; off > 0; off >>= 1) {
        if (tid < off) part[tid] += part[tid + off];
        __syncthreads();
    }
    if (tid == 0) h1[j] = part[0];
}

// ---- fc2 + softmax ----------------------------------------------------------
__global__ __launch_bounds__(64) void k_fc2(const float* __restrict__ h1,
                                            const float* __restrict__ fc1_b,
                                            const float* __restrict__ fc2_w,
                                            const float* __restrict__ fc2_b,
                                            float* __restrict__ out) {
    __shared__ float hv[32];
    __shared__ float lg[5];
    int tid = threadIdx.x;
    if (tid < 32) hv[tid] = eluf(h1[tid] + fc1_b[tid]);
    __syncthreads();
    if (tid < 5) {
        float s = fc2_b[tid];
        for (int j = 0; j < 32; j++) s = fmaf(hv[j], fc2_w[j * 5 + tid], s);
        lg[tid] = s;
    }
    __syncthreads();
    if (tid == 0) {
        float m = lg[0];
        for (int k = 1; k < 5; k++) m = fmaxf(m, lg[k]);
        float e[5], sum = 0.f;
        for (int k = 0; k < 5; k++) { e[k] = expf(lg[k] - m); sum += e[k]; }
        for (int k = 0; k < 5; k++) out[k] = e[k] / sum;
    }
}

extern "C" void kernel_launch(void* const* d_in, const int* in_sizes, int n_in,
                              void* d_out, int out_size, void* d_ws, size_t ws_size,
                              hipStream_t stream) {
    const int* coords = (const int*)d_in[0];
    const float* feats = (const float*)d_in[1];
    const float* w1 = (const float*)d_in[2];
    const float* w2 = (const float*)d_in[3];
    const float* w3 = (const float*)d_in[4];
    const float* w4 = (const float*)d_in[5];
    const float* fc1w = (const float*)d_in[6];
    const float* fc1b = (const float*)d_in[7];
    const float* fc2w = (const float*)d_in[8];
    const float* fc2b = (const float*)d_in[9];
    float* out = (float*)d_out;
    char* ws = (char*)d_ws;
    float* x0 = (float*)(ws + OFF_X0);
    unsigned* m0b = (unsigned*)(ws + OFF_M0B);
    float* y1 = (float*)(ws + OFF_Y1);
    unsigned char* m1g = (unsigned char*)(ws + OFF_M1);
    float* y2 = (float*)(ws + OFF_Y2);
    unsigned char* m2g = (unsigned char*)(ws + OFF_M2);
    float* y3 = (float*)(ws + OFF_Y3);
    unsigned char* m3g = (unsigned char*)(ws + OFF_M3);
    float* y4 = (float*)(ws + OFF_Y4);
    float* h1 = (float*)(ws + OFF_H1);
    int P = in_sizes[1];

    // zero x0 + m0 bitfield
    hipMemsetAsync(ws, 0, OFF_Y1, stream);
    k_scatter<<<(P + 255) / 256, 256, 0, stream>>>(coords, feats, x0, m0b, P);
    k_l1<<<(S1 * S1 + 255) / 256, 256, 0, stream>>>(x0, m0b, w1, y1, m1g);
    k_l2<<<S2 * S2, 64, 0, stream>>>(y1, m1g, w2, y2, m2g);
    k_l3<<<S3 * S3, 256, 0, stream>>>(y2, m2g, w3, y3, m3g);
    k_l4<<<S4 * S4 * 4, 256, 0, stream>>>(y3, m3g, w4, y4);
    k_fc1<<<32, 256, 0, stream>>>(y4, fc1w, h1);
    k_fc2<<<1, 64, 0, stream>>>(h1, fc1b, fc2w, fc2b, out);
}

// Round 4
// 732.134 us; speedup vs baseline: 3.0246x; 1.2909x over previous
//
#include <hip/hip_runtime.h>
#include <math.h>

#define S0 3600
#define S1 720
#define S2 144
#define S3 36
#define S4 9
#define NEGF (-1e30f)

// ---- workspace layout (bytes). Peak 74.72 MB (proven in rounds 2-3).
static constexpr size_t OFF_X0  = 0;                                    // f32 [3600*3600] = 51,840,000
static constexpr size_t OFF_M0B = (size_t)S0 * S0 * 4;                  // u32 bitfield    = 1,620,000
static constexpr size_t OFF_Y1  = OFF_M0B + 1620000;                    // f32 [720*720*10] @53,460,000
static constexpr size_t OFF_M1  = OFF_Y1 + (size_t)S1 * S1 * 10 * 4;    // u8  [720*720]    @74,196,000 (ends 74,714,400)
// aliased into dead x0 region (used from conv2 onward):
static constexpr size_t OFF_Y2  = 0;                                    // f32 [144*144*64]  = 5,308,416
static constexpr size_t OFF_M2  = OFF_Y2 + (size_t)S2 * S2 * 64 * 4;    // u8  [144*144]
static constexpr size_t OFF_Y3  = OFF_M2 + 20736;                       // f32 [36*36*128] @5,329,152
static constexpr size_t OFF_M3  = OFF_Y3 + (size_t)S3 * S3 * 128 * 4;   // u8  [36*36]     @5,992,704
static constexpr size_t OFF_Y4  = OFF_M3 + 1296;                        // f32 [9*9*256]   @5,994,000
static constexpr size_t OFF_H1  = OFF_Y4 + (size_t)S4 * S4 * 256 * 4;   // f32 [32]        @6,076,944
static constexpr size_t OFF_P4  = 6077200;                              // f32 [81*5*16*256] = 6,635,520 (ends 12.7 MB)

__device__ __forceinline__ float eluf(float x) { return x > 0.f ? x : expm1f(x); }
__device__ __forceinline__ int bit_get(const unsigned* mb, int idx) {
    return (mb[idx >> 5] >> (idx & 31)) & 1;
}
__device__ __forceinline__ void fma4(float4& a, float s, const float4& w) {
    a.x = fmaf(s, w.x, a.x); a.y = fmaf(s, w.y, a.y);
    a.z = fmaf(s, w.z, a.z); a.w = fmaf(s, w.w, a.w);
}

// ---- scatter points onto dense grid -----------------------------------------
__global__ __launch_bounds__(256) void k_scatter(const int* __restrict__ coords,
                                                 const float* __restrict__ feats,
                                                 float* __restrict__ x0,
                                                 unsigned* __restrict__ m0b, int P) {
    int i = blockIdx.x * 256 + threadIdx.x;
    if (i >= P) return;
    int r = coords[2 * i], c = coords[2 * i + 1];
    int idx = r * S0 + c;
    atomicAdd(&x0[idx], feats[i]);
    atomicOr(&m0b[idx >> 5], 1u << (idx & 31));
}

// ---- layer 1: conv 5x5 1->10 (gated at active sites) + ELU + maxpool5 -------
__global__ __launch_bounds__(256) void k_l1(const float* __restrict__ x0,
                                            const unsigned* __restrict__ m0b,
                                            const float* __restrict__ w1,
                                            float* __restrict__ y1,
                                            unsigned char* __restrict__ m1) {
    int t = blockIdx.x * 256 + threadIdx.x;
    if (t >= S1 * S1) return;
    int pr = t / S1, pc = t % S1;
    int r0 = pr * 5, c0 = pc * 5;
    float mx[10];
#pragma unroll
    for (int ch = 0; ch < 10; ch++) mx[ch] = NEGF;
    bool any = false;
    for (int dy = 0; dy < 5; dy++) {
        for (int dx = 0; dx < 5; dx++) {
            int rr = r0 + dy, cc = c0 + dx;
            if (!bit_get(m0b, rr * S0 + cc)) continue;
            any = true;
            float acc[10];
#pragma unroll
            for (int ch = 0; ch < 10; ch++) acc[ch] = 0.f;
            for (int ky = 0; ky < 5; ky++) {
                int ir = rr + ky - 2;
                if (ir < 0 || ir >= S0) continue;
                for (int kx = 0; kx < 5; kx++) {
                    int ic = cc + kx - 2;
                    if (ic < 0 || ic >= S0) continue;
                    float xv = x0[(size_t)ir * S0 + ic];
                    const float* wp = &w1[(ky * 5 + kx) * 10];
#pragma unroll
                    for (int ch = 0; ch < 10; ch++) acc[ch] = fmaf(xv, wp[ch], acc[ch]);
                }
            }
#pragma unroll
            for (int ch = 0; ch < 10; ch++) mx[ch] = fmaxf(mx[ch], acc[ch]);
        }
    }
    float* yo = &y1[(size_t)t * 10];
#pragma unroll
    for (int ch = 0; ch < 10; ch++) yo[ch] = any ? eluf(mx[ch]) : 0.f;
    m1[t] = any ? 1 : 0;
}

// ---- layer 2: fused conv 5x5 10->64 (cell-gated) + ELU + maxpool5 -----------
__global__ __launch_bounds__(64) void k_l2(const float* __restrict__ y1,
                                           const unsigned char* __restrict__ m1,
                                           const float* __restrict__ w2,
                                           float* __restrict__ y2,
                                           unsigned char* __restrict__ m2) {
    __shared__ float win[81 * 12];
    __shared__ unsigned char sm[81];
    int b = blockIdx.x;
    int pr = b / S2, pc = b % S2;
    int r0 = pr * 5 - 2, c0 = pc * 5 - 2;
    int tid = threadIdx.x;
    for (int k = tid; k < 81; k += 64) {
        int gr = r0 + k / 9, gc = c0 + k % 9;
        bool ok = (gr >= 0 && gr < S1 && gc >= 0 && gc < S1);
        sm[k] = ok ? m1[gr * S1 + gc] : (unsigned char)0;
        float* dst = &win[k * 12];
        if (ok) {
            const float2* src = (const float2*)&y1[((size_t)gr * S1 + gc) * 10];
#pragma unroll
            for (int q = 0; q < 5; q++) ((float2*)dst)[q] = src[q];
        } else {
#pragma unroll
            for (int q = 0; q < 5; q++) ((float2*)dst)[q] = make_float2(0.f, 0.f);
        }
        dst[10] = 0.f; dst[11] = 0.f;
    }
    __syncthreads();
    int c = tid;
    unsigned mbits = 0;
#pragma unroll
    for (int cell = 0; cell < 25; cell++) {
        if (sm[(2 + cell / 5) * 9 + (2 + cell % 5)]) mbits |= (1u << cell);
    }
    mbits = (unsigned)__builtin_amdgcn_readfirstlane((int)mbits);
    float acc[25];
#pragma unroll
    for (int i = 0; i < 25; i++) acc[i] = 0.f;
    for (int t5 = 0; t5 < 25; t5++) {
        float w[10];
#pragma unroll
        for (int ci = 0; ci < 10; ci++) w[ci] = w2[(t5 * 10 + ci) * 64 + c];
        int base = (t5 / 5) * 9 + (t5 % 5);
#pragma unroll
        for (int cell = 0; cell < 25; cell++) {
            if (mbits & (1u << cell)) {
                const float4* xp = (const float4*)&win[(base + (cell / 5) * 9 + (cell % 5)) * 12];
                float4 xa = xp[0], xb = xp[1], xc = xp[2];
                float a = acc[cell];
                a = fmaf(xa.x, w[0], a); a = fmaf(xa.y, w[1], a);
                a = fmaf(xa.z, w[2], a); a = fmaf(xa.w, w[3], a);
                a = fmaf(xb.x, w[4], a); a = fmaf(xb.y, w[5], a);
                a = fmaf(xb.z, w[6], a); a = fmaf(xb.w, w[7], a);
                a = fmaf(xc.x, w[8], a); a = fmaf(xc.y, w[9], a);
                acc[cell] = a;
            }
        }
    }
    float mx = NEGF;
#pragma unroll
    for (int cell = 0; cell < 25; cell++)
        if (mbits & (1u << cell)) mx = fmaxf(mx, acc[cell]);
    bool any = (mbits != 0);
    y2[((size_t)pr * S2 + pc) * 64 + c] = any ? eluf(mx) : 0.f;
    if (c == 0) m2[pr * S2 + pc] = any ? 1 : 0;
}

// ---- layer 3: fused conv 5x5 64->128 + ELU + maxpool4 -> 36^2 ---------------
// 128 thr/block; thread tile = 4 cells (pc row) x 4 co; 8x8x64 window in LDS.
// Per (t5,ci4) step: 4 LDS b128 (wave-uniform broadcast) + 4 w dwordx4 + 64 FMA.
__global__ __launch_bounds__(128) void k_l3(const float* __restrict__ y2,
                                            const unsigned char* __restrict__ m2,
                                            const float* __restrict__ w3,
                                            float* __restrict__ y3,
                                            unsigned char* __restrict__ m3) {
    __shared__ float win[8 * 8 * 64];   // 16 KB, [cell][ci]
    __shared__ float red[4][128];       // 2 KB
    __shared__ unsigned char sm[16];
    int b = blockIdx.x;                  // 0..1295
    int ppr = b / S3, ppc = b % S3;
    int r0 = ppr * 4 - 2, c0 = ppc * 4 - 2;
    int tid = threadIdx.x;
    float4* win4 = (float4*)win;
    for (int k = tid; k < 1024; k += 128) {
        int cellk = k >> 4, q = k & 15;
        int gr = r0 + (cellk >> 3), gc = c0 + (cellk & 7);
        float4 v = make_float4(0.f, 0.f, 0.f, 0.f);
        if (gr >= 0 && gr < S2 && gc >= 0 && gc < S2)
            v = ((const float4*)y2)[((size_t)gr * S2 + gc) * 16 + q];
        win4[k] = v;
    }
    if (tid < 16) sm[tid] = m2[(ppr * 4 + (tid >> 2)) * S2 + ppc * 4 + (tid & 3)];
    __syncthreads();
    int cq = tid & 31, pr = tid >> 5;    // co-quad 0..31, cell-row 0..3
    int co4 = cq * 4;
    float4 acc[4];
#pragma unroll
    for (int i = 0; i < 4; i++) acc[i] = make_float4(0.f, 0.f, 0.f, 0.f);
#pragma unroll 1
    for (int t5 = 0; t5 < 25; t5++) {
        int ky = t5 / 5, kx = t5 % 5;
        int rowbase = (pr + ky) * 8 + kx;                    // + pc
        const float4* wq = (const float4*)&w3[(size_t)(t5 * 64) * 128 + co4];
#pragma unroll 4
        for (int ci4 = 0; ci4 < 16; ci4++) {
            float4 xv0 = win4[(rowbase + 0) * 16 + ci4];
            float4 xv1 = win4[(rowbase + 1) * 16 + ci4];
            float4 xv2 = win4[(rowbase + 2) * 16 + ci4];
            float4 xv3 = win4[(rowbase + 3) * 16 + ci4];
            float4 w0 = wq[(ci4 * 4 + 0) * 32];
            float4 w1 = wq[(ci4 * 4 + 1) * 32];
            float4 w2v = wq[(ci4 * 4 + 2) * 32];
            float4 w3v = wq[(ci4 * 4 + 3) * 32];
            fma4(acc[0], xv0.x, w0); fma4(acc[0], xv0.y, w1); fma4(acc[0], xv0.z, w2v); fma4(acc[0], xv0.w, w3v);
            fma4(acc[1], xv1.x, w0); fma4(acc[1], xv1.y, w1); fma4(acc[1], xv1.z, w2v); fma4(acc[1], xv1.w, w3v);
            fma4(acc[2], xv2.x, w0); fma4(acc[2], xv2.y, w1); fma4(acc[2], xv2.z, w2v); fma4(acc[2], xv2.w, w3v);
            fma4(acc[3], xv3.x, w0); fma4(acc[3], xv3.y, w1); fma4(acc[3], xv3.z, w2v); fma4(acc[3], xv3.w, w3v);
        }
    }
    // per-thread gated max over its 4 cells (row pr)
    float4 rmax = make_float4(NEGF, NEGF, NEGF, NEGF);
#pragma unroll
    for (int pc = 0; pc < 4; pc++) {
        if (sm[pr * 4 + pc]) {
            rmax.x = fmaxf(rmax.x, acc[pc].x); rmax.y = fmaxf(rmax.y, acc[pc].y);
            rmax.z = fmaxf(rmax.z, acc[pc].z); rmax.w = fmaxf(rmax.w, acc[pc].w);
        }
    }
    *(float4*)&red[pr][co4] = rmax;
    __syncthreads();
    bool any = false;
#pragma unroll
    for (int i = 0; i < 16; i++) any |= (sm[i] != 0);
    if (tid < 32) {
        int c = tid * 4;
        float4 a0 = *(float4*)&red[0][c];
        float4 a1 = *(float4*)&red[1][c];
        float4 a2 = *(float4*)&red[2][c];
        float4 a3 = *(float4*)&red[3][c];
        float4 m;
        m.x = fmaxf(fmaxf(a0.x, a1.x), fmaxf(a2.x, a3.x));
        m.y = fmaxf(fmaxf(a0.y, a1.y), fmaxf(a2.y, a3.y));
        m.z = fmaxf(fmaxf(a0.z, a1.z), fmaxf(a2.z, a3.z));
        m.w = fmaxf(fmaxf(a0.w, a1.w), fmaxf(a2.w, a3.w));
        float4 o;
        o.x = any ? eluf(m.x) : 0.f; o.y = any ? eluf(m.y) : 0.f;
        o.z = any ? eluf(m.z) : 0.f; o.w = any ? eluf(m.w) : 0.f;
        *(float4*)&y3[(size_t)b * 128 + c] = o;
    }
    if (tid == 0) m3[b] = any ? 1 : 0;
}

// ---- layer 4 conv, K-split over ky: block = (pool cell, ky) -----------------
// 256 thr; thread tile = 4 cells x 4 co; window slice 4x8x128 in LDS.
__global__ __launch_bounds__(256) void k_l4(const float* __restrict__ y3,
                                            const float* __restrict__ w4,
                                            float* __restrict__ part) {
    __shared__ float win[4 * 8 * 128];  // 16 KB
    int b = blockIdx.x;                  // 0..404
    int p = b / 5, ky = b % 5;
    int ppr = p / S4, ppc = p % S4;
    int r0 = ppr * 4 - 2 + ky, c0 = ppc * 4 - 2;
    int tid = threadIdx.x;
    float4* win4 = (float4*)win;
    for (int k = tid; k < 1024; k += 256) {
        int cellk = k >> 5, q = k & 31;  // cellk = rr*8+cc, rr 0..3
        int gr = r0 + (cellk >> 3), gc = c0 + (cellk & 7);
        float4 v = make_float4(0.f, 0.f, 0.f, 0.f);
        if (gr >= 0 && gr < S3 && gc >= 0 && gc < S3)
            v = ((const float4*)y3)[((size_t)gr * S3 + gc) * 32 + q];
        win4[k] = v;
    }
    __syncthreads();
    int cq = tid & 63, pr = tid >> 6;    // co-quad 0..63, cell-row 0..3 (one wave per pr)
    int co4 = cq * 4;
    float4 acc[4];
#pragma unroll
    for (int i = 0; i < 4; i++) acc[i] = make_float4(0.f, 0.f, 0.f, 0.f);
#pragma unroll 1
    for (int kx = 0; kx < 5; kx++) {
        int rowbase = pr * 8 + kx;                           // + pc
        const float4* wq = (const float4*)&w4[(size_t)((ky * 5 + kx) * 128) * 256 + co4];
#pragma unroll 4
        for (int ci4 = 0; ci4 < 32; ci4++) {
            float4 xv0 = win4[(rowbase + 0) * 32 + ci4];
            float4 xv1 = win4[(rowbase + 1) * 32 + ci4];
            float4 xv2 = win4[(rowbase + 2) * 32 + ci4];
            float4 xv3 = win4[(rowbase + 3) * 32 + ci4];
            float4 w0 = wq[(ci4 * 4 + 0) * 64];
            float4 w1 = wq[(ci4 * 4 + 1) * 64];
            float4 w2v = wq[(ci4 * 4 + 2) * 64];
            float4 w3v = wq[(ci4 * 4 + 3) * 64];
            fma4(acc[0], xv0.x, w0); fma4(acc[0], xv0.y, w1); fma4(acc[0], xv0.z, w2v); fma4(acc[0], xv0.w, w3v);
            fma4(acc[1], xv1.x, w0); fma4(acc[1], xv1.y, w1); fma4(acc[1], xv1.z, w2v); fma4(acc[1], xv1.w, w3v);
            fma4(acc[2], xv2.x, w0); fma4(acc[2], xv2.y, w1); fma4(acc[2], xv2.z, w2v); fma4(acc[2], xv2.w, w3v);
            fma4(acc[3], xv3.x, w0); fma4(acc[3], xv3.y, w1); fma4(acc[3], xv3.z, w2v); fma4(acc[3], xv3.w, w3v);
        }
    }
#pragma unroll
    for (int pc = 0; pc < 4; pc++) {
        int cell = pr * 4 + pc;
        *(float4*)&part[(((size_t)p * 5 + ky) * 16 + cell) * 256 + co4] = acc[pc];
    }
}

// ---- layer 4 reduce K-partials + ELU + maxpool4 -> 9^2 ----------------------
__global__ __launch_bounds__(256) void k_p4(const float* __restrict__ part,
                                            const unsigned char* __restrict__ m3,
                                            float* __restrict__ y4) {
    int p = blockIdx.x;                  // 0..80
    int co = threadIdx.x;                // 0..255
    int ppr = p / S4, ppc = p % S4;
    float mx = NEGF;
    bool any = false;
    for (int cell = 0; cell < 16; cell++) {
        int site = (ppr * 4 + (cell >> 2)) * S3 + ppc * 4 + (cell & 3);
        if (!m3[site]) continue;
        any = true;
        float s = 0.f;
#pragma unroll
        for (int ky = 0; ky < 5; ky++)
            s += part[(((size_t)p * 5 + ky) * 16 + cell) * 256 + co];
        mx = fmaxf(mx, s);
    }
    y4[(size_t)p * 256 + co] = any ? eluf(mx) : 0.f;
}

// ---- fc1 (deterministic): 32 blocks, block j computes h1[j] -----------------
__global__ __launch_bounds__(256) void k_fc1(const float* __restrict__ y4,
                                             const float* __restrict__ fc1_w,
                                             float* __restrict__ h1) {
    __shared__ float part[256];
    int j = blockIdx.x;                    // 0..31
    int tid = threadIdx.x;
    float s = 0.f;
    for (int i = tid; i < 256 * 81; i += 256) {
        int c = i / 81, rem = i % 81;      // NCHW flatten: i = c*81 + h*9 + w
        s = fmaf(y4[(size_t)rem * 256 + c], fc1_w[(size_t)i * 32 + j], s);
    }
    part[tid] = s;
    __syncthreads();
    for (int off = 128; off > 0; off >>= 1) {
        if (tid < off) part[tid] += part[tid + off];
        __syncthreads();
    }
    if (tid == 0) h1[j] = part[0];
}

// ---- fc2 + softmax ----------------------------------------------------------
__global__ __launch_bounds__(64) void k_fc2(const float* __restrict__ h1,
                                            const float* __restrict__ fc1_b,
                                            const float* __restrict__ fc2_w,
                                            const float* __restrict__ fc2_b,
                                            float* __restrict__ out) {
    __shared__ float hv[32];
    __shared__ float lg[5];
    int tid = threadIdx.x;
    if (tid < 32) hv[tid] = eluf(h1[tid] + fc1_b[tid]);
    __syncthreads();
    if (tid < 5) {
        float s = fc2_b[tid];
        for (int j = 0; j < 32; j++) s = fmaf(hv[j], fc2_w[j * 5 + tid], s);
        lg[tid] = s;
    }
    __syncthreads();
    if (tid == 0) {
        float m = lg[0];
        for (int k = 1; k < 5; k++) m = fmaxf(m, lg[k]);
        float e[5], sum = 0.f;
        for (int k = 0; k < 5; k++) { e[k] = expf(lg[k] - m); sum += e[k]; }
        for (int k = 0; k < 5; k++) out[k] = e[k] / sum;
    }
}

extern "C" void kernel_launch(void* const* d_in, const int* in_sizes, int n_in,
                              void* d_out, int out_size, void* d_ws, size_t ws_size,
                              hipStream_t stream) {
    const int* coords = (const int*)d_in[0];
    const float* feats = (const float*)d_in[1];
    const float* w1 = (const float*)d_in[2];
    const float* w2 = (const float*)d_in[3];
    const float* w3 = (const float*)d_in[4];
    const float* w4 = (const float*)d_in[5];
    const float* fc1w = (const float*)d_in[6];
    const float* fc1b = (const float*)d_in[7];
    const float* fc2w = (const float*)d_in[8];
    const float* fc2b = (const float*)d_in[9];
    float* out = (float*)d_out;
    char* ws = (char*)d_ws;
    float* x0 = (float*)(ws + OFF_X0);
    unsigned* m0b = (unsigned*)(ws + OFF_M0B);
    float* y1 = (float*)(ws + OFF_Y1);
    unsigned char* m1g = (unsigned char*)(ws + OFF_M1);
    float* y2 = (float*)(ws + OFF_Y2);
    unsigned char* m2g = (unsigned char*)(ws + OFF_M2);
    float* y3 = (float*)(ws + OFF_Y3);
    unsigned char* m3g = (unsigned char*)(ws + OFF_M3);
    float* y4 = (float*)(ws + OFF_Y4);
    float* h1 = (float*)(ws + OFF_H1);
    float* p4 = (float*)(ws + OFF_P4);
    int P = in_sizes[1];

    // zero x0 + m0 bitfield (covers aliased y2..p4 regions too)
    hipMemsetAsync(ws, 0, OFF_Y1, stream);
    k_scatter<<<(P + 255) / 256, 256, 0, stream>>>(coords, feats, x0, m0b, P);
    k_l1<<<(S1 * S1 + 255) / 256, 256, 0, stream>>>(x0, m0b, w1, y1, m1g);
    k_l2<<<S2 * S2, 64, 0, stream>>>(y1, m1g, w2, y2, m2g);
    k_l3<<<S3 * S3, 128, 0, stream>>>(y2, m2g, w3, y3, m3g);
    k_l4<<<S4 * S4 * 5, 256, 0, stream>>>(y3, w4, p4);
    k_p4<<<S4 * S4, 256, 0, stream>>>(p4, m3g, y4);
    k_fc1<<<32, 256, 0, stream>>>(y4, fc1w, h1);
    k_fc2<<<1, 64, 0, stream>>>(h1, fc1b, fc2w, fc2b, out);
}

// Round 5
// 532.070 us; speedup vs baseline: 4.1618x; 1.3760x over previous
//
#include <hip/hip_runtime.h>
#include <math.h>

#define S0 3600
#define S1 720
#define S2 144
#define S3 36
#define S4 9
#define NEGF (-1e30f)

// ---- workspace layout (bytes). Peak 74.72 MB (proven in rounds 2-4).
static constexpr size_t OFF_X0  = 0;                                    // f32 [3600*3600] = 51,840,000
static constexpr size_t OFF_M0B = (size_t)S0 * S0 * 4;                  // u32 bitfield    = 1,620,000
static constexpr size_t OFF_Y1  = OFF_M0B + 1620000;                    // f32 [720*720*10] @53,460,000
static constexpr size_t OFF_M1  = OFF_Y1 + (size_t)S1 * S1 * 10 * 4;    // u8  [720*720]    @74,196,000 (ends 74,714,400)
// aliased into dead x0 region (used from conv2 onward):
static constexpr size_t OFF_Y2  = 0;                                    // f32 [144*144*64]  = 5,308,416
static constexpr size_t OFF_M2  = OFF_Y2 + (size_t)S2 * S2 * 64 * 4;    // u8  [144*144]
static constexpr size_t OFF_Y3  = OFF_M2 + 20736;                       // f32 [36*36*128] @5,329,152
static constexpr size_t OFF_M3  = OFF_Y3 + (size_t)S3 * S3 * 128 * 4;   // u8  [36*36]     @5,992,704
static constexpr size_t OFF_Y4  = OFF_M3 + 1296;                        // f32 [9*9*256]   @5,994,000
static constexpr size_t OFF_H1  = OFF_Y4 + (size_t)S4 * S4 * 256 * 4;   // f32 [32]        @6,076,944
static constexpr size_t OFF_P4  = 6077200;                              // f32 [81*5*16*256] = 6,635,520 (ends 12.7 MB)

__device__ __forceinline__ float eluf(float x) { return x > 0.f ? x : expm1f(x); }
__device__ __forceinline__ void fma4(float4& a, float s, const float4& w) {
    a.x = fmaf(s, w.x, a.x); a.y = fmaf(s, w.y, a.y);
    a.z = fmaf(s, w.z, a.z); a.w = fmaf(s, w.w, a.w);
}

// ---- scatter points onto dense grid -----------------------------------------
__global__ __launch_bounds__(256) void k_scatter(const int* __restrict__ coords,
                                                 const float* __restrict__ feats,
                                                 float* __restrict__ x0,
                                                 unsigned* __restrict__ m0b, int P) {
    int i = blockIdx.x * 256 + threadIdx.x;
    if (i >= P) return;
    int r = coords[2 * i], c = coords[2 * i + 1];
    int idx = r * S0 + c;
    atomicAdd(&x0[idx], feats[i]);
    atomicOr(&m0b[idx >> 5], 1u << (idx & 31));
}

// ---- layer 1: sparse conv 5x5 1->10 + ELU + maxpool5 (mask-bitfield-driven) -
// One thread per pool site. Reads the 9x9 patch mask (<=18 word loads), early
// zero-write if the 25 center cells are all inactive (~68% of sites); else
// iterates active cells x active neighbors only (x0 is exactly 0 elsewhere).
__global__ __launch_bounds__(256) void k_l1(const float* __restrict__ x0,
                                            const unsigned* __restrict__ m0b,
                                            const float* __restrict__ w1,
                                            float* __restrict__ y1,
                                            unsigned char* __restrict__ m1) {
    __shared__ float w1s[250];
    int tid = threadIdx.x;
    if (tid < 250) w1s[tid] = w1[tid];
    __syncthreads();
    int t = blockIdx.x * 256 + tid;       // grid exact: 720*720 = 518400
    int pr = t / S1, pc = t % S1;
    int r0 = pr * 5 - 2, c0 = pc * 5 - 2; // 9x9 patch origin
    unsigned rows[9];
#pragma unroll
    for (int rr = 0; rr < 9; rr++) {
        unsigned bits = 0;
        int gr = r0 + rr;
        if (gr >= 0 && gr < S0) {
            int cs = c0 < 0 ? 0 : c0;
            int ce = c0 + 8 > S0 - 1 ? S0 - 1 : c0 + 8;
            int span = ce - cs;
            size_t i0 = (size_t)gr * S0 + cs;
            unsigned sh = (unsigned)(i0 & 31);
            unsigned long long two = (unsigned long long)m0b[i0 >> 5] >> sh;
            if ((int)sh + span >= 32)
                two |= (unsigned long long)m0b[(i0 >> 5) + 1] << (32 - sh);
            bits = (unsigned)(two & ((1u << (span + 1)) - 1));
            bits <<= (cs - c0);
        }
        rows[rr] = bits;
    }
    unsigned any25 = 0;
#pragma unroll
    for (int dy = 0; dy < 5; dy++) any25 |= (rows[2 + dy] >> 2) & 0x1Fu;
    float* yo = &y1[(size_t)t * 10];
    if (!any25) {
#pragma unroll
        for (int q = 0; q < 5; q++) ((float2*)yo)[q] = make_float2(0.f, 0.f);
        m1[t] = 0;
        return;
    }
    float2 mx[5];
#pragma unroll
    for (int q = 0; q < 5; q++) mx[q] = make_float2(NEGF, NEGF);
    for (int dy = 0; dy < 5; dy++) {
        unsigned crow = (rows[2 + dy] >> 2) & 0x1Fu;
        while (crow) {
            int dx = __ffs(crow) - 1; crow &= crow - 1;
            float2 acc[5];
#pragma unroll
            for (int q = 0; q < 5; q++) acc[q] = make_float2(0.f, 0.f);
#pragma unroll
            for (int ky = 0; ky < 5; ky++) {
                unsigned nrow = (rows[dy + ky] >> dx) & 0x1Fu;
                size_t rowbase = (size_t)(r0 + dy + ky) * S0 + (c0 + dx);
                while (nrow) {
                    int kx = __ffs(nrow) - 1; nrow &= nrow - 1;
                    float xv = x0[rowbase + kx];
                    const float2* wp = (const float2*)&w1s[(ky * 5 + kx) * 10];
#pragma unroll
                    for (int q = 0; q < 5; q++) {
                        float2 w = wp[q];
                        acc[q].x = fmaf(xv, w.x, acc[q].x);
                        acc[q].y = fmaf(xv, w.y, acc[q].y);
                    }
                }
            }
#pragma unroll
            for (int q = 0; q < 5; q++) {
                mx[q].x = fmaxf(mx[q].x, acc[q].x);
                mx[q].y = fmaxf(mx[q].y, acc[q].y);
            }
        }
    }
#pragma unroll
    for (int q = 0; q < 5; q++) {
        float2 o;
        o.x = eluf(mx[q].x); o.y = eluf(mx[q].y);
        ((float2*)yo)[q] = o;
    }
    m1[t] = 1;
}

// ---- layer 2: fused conv 5x5 10->64 (cell-gated) + ELU + maxpool5 -----------
__global__ __launch_bounds__(64) void k_l2(const float* __restrict__ y1,
                                           const unsigned char* __restrict__ m1,
                                           const float* __restrict__ w2,
                                           float* __restrict__ y2,
                                           unsigned char* __restrict__ m2) {
    __shared__ float win[81 * 12];
    __shared__ unsigned char sm[81];
    int b = blockIdx.x;
    int pr = b / S2, pc = b % S2;
    int r0 = pr * 5 - 2, c0 = pc * 5 - 2;
    int tid = threadIdx.x;
    for (int k = tid; k < 81; k += 64) {
        int gr = r0 + k / 9, gc = c0 + k % 9;
        bool ok = (gr >= 0 && gr < S1 && gc >= 0 && gc < S1);
        sm[k] = ok ? m1[gr * S1 + gc] : (unsigned char)0;
        float* dst = &win[k * 12];
        if (ok) {
            const float2* src = (const float2*)&y1[((size_t)gr * S1 + gc) * 10];
#pragma unroll
            for (int q = 0; q < 5; q++) ((float2*)dst)[q] = src[q];
        } else {
#pragma unroll
            for (int q = 0; q < 5; q++) ((float2*)dst)[q] = make_float2(0.f, 0.f);
        }
        dst[10] = 0.f; dst[11] = 0.f;
    }
    __syncthreads();
    int c = tid;
    unsigned mbits = 0;
#pragma unroll
    for (int cell = 0; cell < 25; cell++) {
        if (sm[(2 + cell / 5) * 9 + (2 + cell % 5)]) mbits |= (1u << cell);
    }
    mbits = (unsigned)__builtin_amdgcn_readfirstlane((int)mbits);
    float acc[25];
#pragma unroll
    for (int i = 0; i < 25; i++) acc[i] = 0.f;
    for (int t5 = 0; t5 < 25; t5++) {
        float w[10];
#pragma unroll
        for (int ci = 0; ci < 10; ci++) w[ci] = w2[(t5 * 10 + ci) * 64 + c];
        int base = (t5 / 5) * 9 + (t5 % 5);
#pragma unroll
        for (int cell = 0; cell < 25; cell++) {
            if (mbits & (1u << cell)) {
                const float4* xp = (const float4*)&win[(base + (cell / 5) * 9 + (cell % 5)) * 12];
                float4 xa = xp[0], xb = xp[1], xc = xp[2];
                float a = acc[cell];
                a = fmaf(xa.x, w[0], a); a = fmaf(xa.y, w[1], a);
                a = fmaf(xa.z, w[2], a); a = fmaf(xa.w, w[3], a);
                a = fmaf(xb.x, w[4], a); a = fmaf(xb.y, w[5], a);
                a = fmaf(xb.z, w[6], a); a = fmaf(xb.w, w[7], a);
                a = fmaf(xc.x, w[8], a); a = fmaf(xc.y, w[9], a);
                acc[cell] = a;
            }
        }
    }
    float mx = NEGF;
#pragma unroll
    for (int cell = 0; cell < 25; cell++)
        if (mbits & (1u << cell)) mx = fmaxf(mx, acc[cell]);
    bool any = (mbits != 0);
    y2[((size_t)pr * S2 + pc) * 64 + c] = any ? eluf(mx) : 0.f;
    if (c == 0) m2[pr * S2 + pc] = any ? 1 : 0;
}

// ---- layer 3: fused conv 5x5 64->128 + ELU + maxpool4 -> 36^2 ---------------
// 128 thr/block; thread tile = 4 cells (pc row) x 4 co; 8x8x64 window in LDS.
__global__ __launch_bounds__(128) void k_l3(const float* __restrict__ y2,
                                            const unsigned char* __restrict__ m2,
                                            const float* __restrict__ w3,
                                            float* __restrict__ y3,
                                            unsigned char* __restrict__ m3) {
    __shared__ float win[8 * 8 * 64];   // 16 KB, [cell][ci]
    __shared__ float red[4][128];       // 2 KB
    __shared__ unsigned char sm[16];
    int b = blockIdx.x;                  // 0..1295
    int ppr = b / S3, ppc = b % S3;
    int r0 = ppr * 4 - 2, c0 = ppc * 4 - 2;
    int tid = threadIdx.x;
    float4* win4 = (float4*)win;
    for (int k = tid; k < 1024; k += 128) {
        int cellk = k >> 4, q = k & 15;
        int gr = r0 + (cellk >> 3), gc = c0 + (cellk & 7);
        float4 v = make_float4(0.f, 0.f, 0.f, 0.f);
        if (gr >= 0 && gr < S2 && gc >= 0 && gc < S2)
            v = ((const float4*)y2)[((size_t)gr * S2 + gc) * 16 + q];
        win4[k] = v;
    }
    if (tid < 16) sm[tid] = m2[(ppr * 4 + (tid >> 2)) * S2 + ppc * 4 + (tid & 3)];
    __syncthreads();
    int cq = tid & 31, pr = tid >> 5;    // co-quad 0..31, cell-row 0..3
    int co4 = cq * 4;
    float4 acc[4];
#pragma unroll
    for (int i = 0; i < 4; i++) acc[i] = make_float4(0.f, 0.f, 0.f, 0.f);
#pragma unroll 1
    for (int t5 = 0; t5 < 25; t5++) {
        int ky = t5 / 5, kx = t5 % 5;
        int rowbase = (pr + ky) * 8 + kx;                    // + pc
        const float4* wq = (const float4*)&w3[(size_t)(t5 * 64) * 128 + co4];
#pragma unroll 4
        for (int ci4 = 0; ci4 < 16; ci4++) {
            float4 xv0 = win4[(rowbase + 0) * 16 + ci4];
            float4 xv1 = win4[(rowbase + 1) * 16 + ci4];
            float4 xv2 = win4[(rowbase + 2) * 16 + ci4];
            float4 xv3 = win4[(rowbase + 3) * 16 + ci4];
            float4 w0 = wq[(ci4 * 4 + 0) * 32];
            float4 w1 = wq[(ci4 * 4 + 1) * 32];
            float4 w2v = wq[(ci4 * 4 + 2) * 32];
            float4 w3v = wq[(ci4 * 4 + 3) * 32];
            fma4(acc[0], xv0.x, w0); fma4(acc[0], xv0.y, w1); fma4(acc[0], xv0.z, w2v); fma4(acc[0], xv0.w, w3v);
            fma4(acc[1], xv1.x, w0); fma4(acc[1], xv1.y, w1); fma4(acc[1], xv1.z, w2v); fma4(acc[1], xv1.w, w3v);
            fma4(acc[2], xv2.x, w0); fma4(acc[2], xv2.y, w1); fma4(acc[2], xv2.z, w2v); fma4(acc[2], xv2.w, w3v);
            fma4(acc[3], xv3.x, w0); fma4(acc[3], xv3.y, w1); fma4(acc[3], xv3.z, w2v); fma4(acc[3], xv3.w, w3v);
        }
    }
    float4 rmax = make_float4(NEGF, NEGF, NEGF, NEGF);
#pragma unroll
    for (int pc = 0; pc < 4; pc++) {
        if (sm[pr * 4 + pc]) {
            rmax.x = fmaxf(rmax.x, acc[pc].x); rmax.y = fmaxf(rmax.y, acc[pc].y);
            rmax.z = fmaxf(rmax.z, acc[pc].z); rmax.w = fmaxf(rmax.w, acc[pc].w);
        }
    }
    *(float4*)&red[pr][co4] = rmax;
    __syncthreads();
    bool any = false;
#pragma unroll
    for (int i = 0; i < 16; i++) any |= (sm[i] != 0);
    if (tid < 32) {
        int c = tid * 4;
        float4 a0 = *(float4*)&red[0][c];
        float4 a1 = *(float4*)&red[1][c];
        float4 a2 = *(float4*)&red[2][c];
        float4 a3 = *(float4*)&red[3][c];
        float4 m;
        m.x = fmaxf(fmaxf(a0.x, a1.x), fmaxf(a2.x, a3.x));
        m.y = fmaxf(fmaxf(a0.y, a1.y), fmaxf(a2.y, a3.y));
        m.z = fmaxf(fmaxf(a0.z, a1.z), fmaxf(a2.z, a3.z));
        m.w = fmaxf(fmaxf(a0.w, a1.w), fmaxf(a2.w, a3.w));
        float4 o;
        o.x = any ? eluf(m.x) : 0.f; o.y = any ? eluf(m.y) : 0.f;
        o.z = any ? eluf(m.z) : 0.f; o.w = any ? eluf(m.w) : 0.f;
        *(float4*)&y3[(size_t)b * 128 + c] = o;
    }
    if (tid == 0) m3[b] = any ? 1 : 0;
}

// ---- layer 4 conv, K-split over ky: block = (pool cell, ky) -----------------
__global__ __launch_bounds__(256) void k_l4(const float* __restrict__ y3,
                                            const float* __restrict__ w4,
                                            float* __restrict__ part) {
    __shared__ float win[4 * 8 * 128];  // 16 KB
    int b = blockIdx.x;                  // 0..404
    int p = b / 5, ky = b % 5;
    int ppr = p / S4, ppc = p % S4;
    int r0 = ppr * 4 - 2 + ky, c0 = ppc * 4 - 2;
    int tid = threadIdx.x;
    float4* win4 = (float4*)win;
    for (int k = tid; k < 1024; k += 256) {
        int cellk = k >> 5, q = k & 31;  // cellk = rr*8+cc, rr 0..3
        int gr = r0 + (cellk >> 3), gc = c0 + (cellk & 7);
        float4 v = make_float4(0.f, 0.f, 0.f, 0.f);
        if (gr >= 0 && gr < S3 && gc >= 0 && gc < S3)
            v = ((const float4*)y3)[((size_t)gr * S3 + gc) * 32 + q];
        win4[k] = v;
    }
    __syncthreads();
    int cq = tid & 63, pr = tid >> 6;    // co-quad 0..63, cell-row 0..3
    int co4 = cq * 4;
    float4 acc[4];
#pragma unroll
    for (int i = 0; i < 4; i++) acc[i] = make_float4(0.f, 0.f, 0.f, 0.f);
#pragma unroll 1
    for (int kx = 0; kx < 5; kx++) {
        int rowbase = pr * 8 + kx;                           // + pc
        const float4* wq = (const float4*)&w4[(size_t)((ky * 5 + kx) * 128) * 256 + co4];
#pragma unroll 4
        for (int ci4 = 0; ci4 < 32; ci4++) {
            float4 xv0 = win4[(rowbase + 0) * 32 + ci4];
            float4 xv1 = win4[(rowbase + 1) * 32 + ci4];
            float4 xv2 = win4[(rowbase + 2) * 32 + ci4];
            float4 xv3 = win4[(rowbase + 3) * 32 + ci4];
            float4 w0 = wq[(ci4 * 4 + 0) * 64];
            float4 w1 = wq[(ci4 * 4 + 1) * 64];
            float4 w2v = wq[(ci4 * 4 + 2) * 64];
            float4 w3v = wq[(ci4 * 4 + 3) * 64];
            fma4(acc[0], xv0.x, w0); fma4(acc[0], xv0.y, w1); fma4(acc[0], xv0.z, w2v); fma4(acc[0], xv0.w, w3v);
            fma4(acc[1], xv1.x, w0); fma4(acc[1], xv1.y, w1); fma4(acc[1], xv1.z, w2v); fma4(acc[1], xv1.w, w3v);
            fma4(acc[2], xv2.x, w0); fma4(acc[2], xv2.y, w1); fma4(acc[2], xv2.z, w2v); fma4(acc[2], xv2.w, w3v);
            fma4(acc[3], xv3.x, w0); fma4(acc[3], xv3.y, w1); fma4(acc[3], xv3.z, w2v); fma4(acc[3], xv3.w, w3v);
        }
    }
#pragma unroll
    for (int pc = 0; pc < 4; pc++) {
        int cell = pr * 4 + pc;
        *(float4*)&part[(((size_t)p * 5 + ky) * 16 + cell) * 256 + co4] = acc[pc];
    }
}

// ---- layer 4 reduce K-partials + ELU + maxpool4 -> 9^2 ----------------------
__global__ __launch_bounds__(256) void k_p4(const float* __restrict__ part,
                                            const unsigned char* __restrict__ m3,
                                            float* __restrict__ y4) {
    int p = blockIdx.x;                  // 0..80
    int co = threadIdx.x;                // 0..255
    int ppr = p / S4, ppc = p % S4;
    float mx = NEGF;
    bool any = false;
    for (int cell = 0; cell < 16; cell++) {
        int site = (ppr * 4 + (cell >> 2)) * S3 + ppc * 4 + (cell & 3);
        if (!m3[site]) continue;
        any = true;
        float s = 0.f;
#pragma unroll
        for (int ky = 0; ky < 5; ky++)
            s += part[(((size_t)p * 5 + ky) * 16 + cell) * 256 + co];
        mx = fmaxf(mx, s);
    }
    y4[(size_t)p * 256 + co] = any ? eluf(mx) : 0.f;
}

// ---- fc1 (deterministic): 32 blocks, block j computes h1[j] -----------------
__global__ __launch_bounds__(256) void k_fc1(const float* __restrict__ y4,
                                             const float* __restrict__ fc1_w,
                                             float* __restrict__ h1) {
    __shared__ float part[256];
    int j = blockIdx.x;                    // 0..31
    int tid = threadIdx.x;
    float s = 0.f;
    for (int i = tid; i < 256 * 81; i += 256) {
        int c = i / 81, rem = i % 81;      // NCHW flatten: i = c*81 + h*9 + w
        s = fmaf(y4[(size_t)rem * 256 + c], fc1_w[(size_t)i * 32 + j], s);
    }
    part[tid] = s;
    __syncthreads();
    for (int off = 128; off > 0; off >>= 1) {
        if (tid < off) part[tid] += part[tid + off];
        __syncthreads();
    }
    if (tid == 0) h1[j] = part[0];
}

// ---- fc2 + softmax ----------------------------------------------------------
__global__ __launch_bounds__(64) void k_fc2(const float* __restrict__ h1,
                                            const float* __restrict__ fc1_b,
                                            const float* __restrict__ fc2_w,
                                            const float* __restrict__ fc2_b,
                                            float* __restrict__ out) {
    __shared__ float hv[32];
    __shared__ float lg[5];
    int tid = threadIdx.x;
    if (tid < 32) hv[tid] = eluf(h1[tid] + fc1_b[tid]);
    __syncthreads();
    if (tid < 5) {
        float s = fc2_b[tid];
        for (int j = 0; j < 32; j++) s = fmaf(hv[j], fc2_w[j * 5 + tid], s);
        lg[tid] = s;
    }
    __syncthreads();
    if (tid == 0) {
        float m = lg[0];
        for (int k = 1; k < 5; k++) m = fmaxf(m, lg[k]);
        float e[5], sum = 0.f;
        for (int k = 0; k < 5; k++) { e[k] = expf(lg[k] - m); sum += e[k]; }
        for (int k = 0; k < 5; k++) out[k] = e[k] / sum;
    }
}

extern "C" void kernel_launch(void* const* d_in, const int* in_sizes, int n_in,
                              void* d_out, int out_size, void* d_ws, size_t ws_size,
                              hipStream_t stream) {
    const int* coords = (const int*)d_in[0];
    const float* feats = (const float*)d_in[1];
    const float* w1 = (const float*)d_in[2];
    const float* w2 = (const float*)d_in[3];
    const float* w3 = (const float*)d_in[4];
    const float* w4 = (const float*)d_in[5];
    const float* fc1w = (const float*)d_in[6];
    const float* fc1b = (const float*)d_in[7];
    const float* fc2w = (const float*)d_in[8];
    const float* fc2b = (const float*)d_in[9];
    float* out = (float*)d_out;
    char* ws = (char*)d_ws;
    float* x0 = (float*)(ws + OFF_X0);
    unsigned* m0b = (unsigned*)(ws + OFF_M0B);
    float* y1 = (float*)(ws + OFF_Y1);
    unsigned char* m1g = (unsigned char*)(ws + OFF_M1);
    float* y2 = (float*)(ws + OFF_Y2);
    unsigned char* m2g = (unsigned char*)(ws + OFF_M2);
    float* y3 = (float*)(ws + OFF_Y3);
    unsigned char* m3g = (unsigned char*)(ws + OFF_M3);
    float* y4 = (float*)(ws + OFF_Y4);
    float* h1 = (float*)(ws + OFF_H1);
    float* p4 = (float*)(ws + OFF_P4);
    int P = in_sizes[1];

    // zero x0 + m0 bitfield (covers aliased y2..p4 regions too)
    hipMemsetAsync(ws, 0, OFF_Y1, stream);
    k_scatter<<<(P + 255) / 256, 256, 0, stream>>>(coords, feats, x0, m0b, P);
    k_l1<<<(S1 * S1) / 256, 256, 0, stream>>>(x0, m0b, w1, y1, m1g);
    k_l2<<<S2 * S2, 64, 0, stream>>>(y1, m1g, w2, y2, m2g);
    k_l3<<<S3 * S3, 128, 0, stream>>>(y2, m2g, w3, y3, m3g);
    k_l4<<<S4 * S4 * 5, 256, 0, stream>>>(y3, w4, p4);
    k_p4<<<S4 * S4, 256, 0, stream>>>(p4, m3g, y4);
    k_fc1<<<32, 256, 0, stream>>>(y4, fc1w, h1);
    k_fc2<<<1, 64, 0, stream>>>(h1, fc1b, fc2w, fc2b, out);
}